// Round 1
// baseline (315.118 us; speedup 1.0000x reference)
//
#include <hip/hip_runtime.h>
#include <hip/hip_bf16.h>

typedef float f32x4 __attribute__((ext_vector_type(4)));
typedef __bf16 bf16x8 __attribute__((ext_vector_type(8)));

#define T_SEQ 2048
#define D_EMB 1024
#define H_DIM 128
#define NBATCH 8
#define NTOK 16384  // NBATCH * T_SEQ

// ---------------------------------------------------------------------------
// ws layout (bf16 elements):
//   Wt : [3][128][1024]   transposed weights (W^T), q|k|v
//   qb : [16384][128]     Q bf16
//   kb : [16384][128]     K bf16
//   vt : [8][128][2048]   V transposed per batch (so PV B-frags are contiguous)
// total = 393216 + 3*2097152 = 6,684,672 bf16 = ~12.8 MB
// ---------------------------------------------------------------------------

__global__ __launch_bounds__(256) void prep_w_kernel(
    const float* __restrict__ Wq, const float* __restrict__ Wk,
    const float* __restrict__ Wv, __hip_bfloat16* __restrict__ Wt) {
  const int mat = blockIdx.x >> 7;   // 0..2
  const int h = blockIdx.x & 127;
  const float* W = (mat == 0) ? Wq : ((mat == 1) ? Wk : Wv);
  __hip_bfloat16* dst = Wt + (size_t)(mat * 128 + h) * D_EMB;
  for (int k = threadIdx.x; k < D_EMB; k += 256)
    dst[k] = __float2bfloat16(W[(size_t)k * H_DIM + h]);
}

// Projection GEMM: out[64, 384] per block. A = x (fp32 -> bf16 via LDS),
// B = Wt (bf16, contiguous k per row). MFMA 16x16x32 bf16.
// A-frag: lane holds A[row = lane&15][k = (lane>>4)*8 + j]
// B-frag: lane holds B[k = (lane>>4)*8 + j][col = lane&15]  (reads Wt[col][k..])
// C/D  : col = lane&15, row = (lane>>4)*4 + reg   (verified layout)
__global__ __launch_bounds__(256) void proj_kernel(
    const float* __restrict__ x, const __hip_bfloat16* __restrict__ Wt,
    __hip_bfloat16* __restrict__ qb, __hip_bfloat16* __restrict__ kb,
    __hip_bfloat16* __restrict__ vt) {
  __shared__ __align__(16) __hip_bfloat16 As[64][40];  // 64 rows x 32 k (+8 pad)
  const int tid = threadIdx.x;
  const int wave = tid >> 6;
  const int lane = tid & 63;
  const int g = lane >> 4;
  const int lr = lane & 15;
  const int m0 = blockIdx.x * 64;

  f32x4 acc[24];
#pragma unroll
  for (int i = 0; i < 24; ++i) acc[i] = f32x4{0.f, 0.f, 0.f, 0.f};

  const int srow = tid >> 2;        // 0..63
  const int scol = (tid & 3) * 8;   // 0,8,16,24

  for (int k0 = 0; k0 < D_EMB; k0 += 32) {
    __syncthreads();
    {
      const float* src = x + (size_t)(m0 + srow) * D_EMB + k0 + scol;
      float4 f0 = *reinterpret_cast<const float4*>(src);
      float4 f1 = *reinterpret_cast<const float4*>(src + 4);
      __hip_bfloat16* dst = &As[srow][scol];
      dst[0] = __float2bfloat16(f0.x);
      dst[1] = __float2bfloat16(f0.y);
      dst[2] = __float2bfloat16(f0.z);
      dst[3] = __float2bfloat16(f0.w);
      dst[4] = __float2bfloat16(f1.x);
      dst[5] = __float2bfloat16(f1.y);
      dst[6] = __float2bfloat16(f1.z);
      dst[7] = __float2bfloat16(f1.w);
    }
    __syncthreads();
    bf16x8 a = *reinterpret_cast<const bf16x8*>(&As[wave * 16 + lr][g * 8]);
#pragma unroll
    for (int nt = 0; nt < 24; ++nt) {
      const __hip_bfloat16* bp =
          Wt + (size_t)(nt * 16 + lr) * D_EMB + k0 + g * 8;
      bf16x8 bfr = *reinterpret_cast<const bf16x8*>(bp);
      acc[nt] = __builtin_amdgcn_mfma_f32_16x16x32_bf16(a, bfr, acc[nt], 0, 0, 0);
    }
  }

  const int rowbase = m0 + wave * 16 + g * 4;
#pragma unroll
  for (int nt = 0; nt < 24; ++nt) {
    const int n = nt * 16 + lr;   // 0..383
    const int head = n >> 7;      // 0:q 1:k 2:v
    const int h = n & 127;
#pragma unroll
    for (int r = 0; r < 4; ++r) {
      const int row = rowbase + r;  // global token index
      const __hip_bfloat16 val = __float2bfloat16(acc[nt][r]);
      if (head == 0) {
        qb[(size_t)row * H_DIM + h] = val;
      } else if (head == 1) {
        kb[(size_t)row * H_DIM + h] = val;
      } else {
        const int bi = row >> 11;          // /T_SEQ
        const int t = row & (T_SEQ - 1);
        vt[((size_t)bi * H_DIM + h) * T_SEQ + t] = val;
      }
    }
  }
}

// Flash attention: grid = B * (T/64). 4 independent waves per block,
// each wave owns 16 q rows; iterates keys in blocks of 32 with online softmax.
__global__ __launch_bounds__(256) void attn_kernel(
    const __hip_bfloat16* __restrict__ qb, const __hip_bfloat16* __restrict__ kb,
    const __hip_bfloat16* __restrict__ vt, float* __restrict__ out) {
  __shared__ __align__(16) __hip_bfloat16 Pl[4][16][40];  // per-wave P tile
  const int tid = threadIdx.x;
  const int wave = tid >> 6;
  const int lane = tid & 63;
  const int g = lane >> 4;
  const int lr = lane & 15;
  const int blk = blockIdx.x;
  const int b = blk >> 5;            // 32 q-blocks per batch
  const int t0 = (blk & 31) * 64;
  const int qrow0 = t0 + wave * 16;  // this wave's first q row (in batch)

  const __hip_bfloat16* qB = qb + (size_t)b * T_SEQ * H_DIM;
  const __hip_bfloat16* kB = kb + (size_t)b * T_SEQ * H_DIM;
  const __hip_bfloat16* vB = vt + (size_t)b * H_DIM * T_SEQ;

  // Q A-fragments for all 4 k-chunks of 32 dims, hoisted
  bf16x8 qf[4];
#pragma unroll
  for (int kt = 0; kt < 4; ++kt)
    qf[kt] = *reinterpret_cast<const bf16x8*>(
        qB + (size_t)(qrow0 + lr) * H_DIM + kt * 32 + g * 8);

  f32x4 oacc[8];
#pragma unroll
  for (int i = 0; i < 8; ++i) oacc[i] = f32x4{0.f, 0.f, 0.f, 0.f};
  float mrow[4] = {-1e30f, -1e30f, -1e30f, -1e30f};
  float lrow[4] = {0.f, 0.f, 0.f, 0.f};

  const float scale = 0.08838834764831845f;  // 1/sqrt(128)
  const int smax = qrow0 + 16;  // need keys 0 .. qrow0+15

  for (int s0 = 0; s0 < smax; s0 += 32) {
    // ---- S = Q K^T for 16 rows x 32 keys ----
    f32x4 sacc[2];
    sacc[0] = f32x4{0.f, 0.f, 0.f, 0.f};
    sacc[1] = f32x4{0.f, 0.f, 0.f, 0.f};
#pragma unroll
    for (int nt = 0; nt < 2; ++nt) {
#pragma unroll
      for (int kt = 0; kt < 4; ++kt) {
        bf16x8 kf = *reinterpret_cast<const bf16x8*>(
            kB + (size_t)(s0 + nt * 16 + lr) * H_DIM + kt * 32 + g * 8);
        sacc[nt] =
            __builtin_amdgcn_mfma_f32_16x16x32_bf16(qf[kt], kf, sacc[nt], 0, 0, 0);
      }
    }
    // ---- scale + causal mask ----
    float sv[2][4];
#pragma unroll
    for (int nt = 0; nt < 2; ++nt)
#pragma unroll
      for (int r = 0; r < 4; ++r) {
        const int key = s0 + nt * 16 + lr;
        const int qr = qrow0 + g * 4 + r;
        const float s = sacc[nt][r] * scale;
        sv[nt][r] = (key > qr) ? -1e30f : s;
      }
    // ---- row max over 32 keys (regs + 16-lane butterfly) ----
    float pm[4];
#pragma unroll
    for (int r = 0; r < 4; ++r) pm[r] = fmaxf(sv[0][r], sv[1][r]);
#pragma unroll
    for (int m = 1; m < 16; m <<= 1)
#pragma unroll
      for (int r = 0; r < 4; ++r) pm[r] = fmaxf(pm[r], __shfl_xor(pm[r], m, 64));
    // ---- online softmax update ----
    float corr[4];
#pragma unroll
    for (int r = 0; r < 4; ++r) {
      const float mnew = fmaxf(mrow[r], pm[r]);
      corr[r] = __expf(mrow[r] - mnew);
      mrow[r] = mnew;
    }
    float rs[4];
#pragma unroll
    for (int r = 0; r < 4; ++r) {
      const float p0 = __expf(sv[0][r] - mrow[r]);
      const float p1 = __expf(sv[1][r] - mrow[r]);
      Pl[wave][g * 4 + r][lr] = __float2bfloat16(p0);
      Pl[wave][g * 4 + r][16 + lr] = __float2bfloat16(p1);
      rs[r] = p0 + p1;
    }
#pragma unroll
    for (int m = 1; m < 16; m <<= 1)
#pragma unroll
      for (int r = 0; r < 4; ++r) rs[r] += __shfl_xor(rs[r], m, 64);
#pragma unroll
    for (int r = 0; r < 4; ++r) lrow[r] = lrow[r] * corr[r] + rs[r];
#pragma unroll
    for (int ht = 0; ht < 8; ++ht)
#pragma unroll
      for (int r = 0; r < 4; ++r) oacc[ht][r] *= corr[r];

    // ---- PV: A = P[16x32] (via LDS re-layout), B = V^T rows ----
    asm volatile("" ::: "memory");  // keep ds_writes above ds_read (wave lockstep)
    bf16x8 pf = *reinterpret_cast<const bf16x8*>(&Pl[wave][lr][g * 8]);
#pragma unroll
    for (int ht = 0; ht < 8; ++ht) {
      bf16x8 vf = *reinterpret_cast<const bf16x8*>(
          vB + (size_t)(ht * 16 + lr) * T_SEQ + s0 + g * 8);
      oacc[ht] = __builtin_amdgcn_mfma_f32_16x16x32_bf16(pf, vf, oacc[ht], 0, 0, 0);
    }
  }

  // ---- epilogue: normalize and store fp32 ----
#pragma unroll
  for (int ht = 0; ht < 8; ++ht)
#pragma unroll
    for (int r = 0; r < 4; ++r) {
      const int qr = qrow0 + g * 4 + r;
      out[((size_t)b * T_SEQ + qr) * H_DIM + ht * 16 + lr] =
          oacc[ht][r] / lrow[r];
    }
}

extern "C" void kernel_launch(void* const* d_in, const int* in_sizes, int n_in,
                              void* d_out, int out_size, void* d_ws, size_t ws_size,
                              hipStream_t stream) {
  const float* x = (const float*)d_in[0];
  const float* Wq = (const float*)d_in[1];
  const float* Wk = (const float*)d_in[2];
  const float* Wv = (const float*)d_in[3];
  float* out = (float*)d_out;

  __hip_bfloat16* Wt = (__hip_bfloat16*)d_ws;
  __hip_bfloat16* qbuf = Wt + (size_t)3 * 128 * 1024;
  __hip_bfloat16* kbuf = qbuf + (size_t)NTOK * H_DIM;
  __hip_bfloat16* vbuf = kbuf + (size_t)NTOK * H_DIM;

  hipLaunchKernelGGL(prep_w_kernel, dim3(384), dim3(256), 0, stream, Wq, Wk, Wv, Wt);
  hipLaunchKernelGGL(proj_kernel, dim3(256), dim3(256), 0, stream, x, Wt, qbuf,
                     kbuf, vbuf);
  hipLaunchKernelGGL(attn_kernel, dim3(256), dim3(256), 0, stream, qbuf, kbuf,
                     vbuf, out);
}

// Round 2
// 181.263 us; speedup vs baseline: 1.7385x; 1.7385x over previous
//
#include <hip/hip_runtime.h>
#include <hip/hip_bf16.h>

typedef float f32x4 __attribute__((ext_vector_type(4)));
typedef __bf16 bf16x8 __attribute__((ext_vector_type(8)));

#define T_SEQ 2048
#define D_EMB 1024
#define H_DIM 128
#define NBATCH 8
#define NTOK 16384  // NBATCH * T_SEQ

// ---------------------------------------------------------------------------
// ws layout (bf16 elements):
//   Wt : [3][128][1024]   transposed weights (W^T), q|k|v
//   qb : [16384][128]     Q bf16
//   kb : [16384][128]     K bf16
//   vt : [8][128][2048]   V transposed per batch (PV B-frags contiguous)
// ---------------------------------------------------------------------------

__global__ __launch_bounds__(256) void prep_w_kernel(
    const float* __restrict__ Wq, const float* __restrict__ Wk,
    const float* __restrict__ Wv, __hip_bfloat16* __restrict__ Wt) {
  const int mat = blockIdx.x >> 7;   // 0..2
  const int h = blockIdx.x & 127;
  const float* W = (mat == 0) ? Wq : ((mat == 1) ? Wk : Wv);
  __hip_bfloat16* dst = Wt + (size_t)(mat * 128 + h) * D_EMB;
  for (int k = threadIdx.x; k < D_EMB; k += 256)
    dst[k] = __float2bfloat16(W[(size_t)k * H_DIM + h]);
}

// Projection GEMM: out[32 rows, 384 cols] per block, 8 waves:
// wave w: rows (w&1)*16, col-tiles nt = (w>>1)*6 .. +5. k-step 64.
__global__ __launch_bounds__(512) void proj_kernel(
    const float* __restrict__ x, const __hip_bfloat16* __restrict__ Wt,
    __hip_bfloat16* __restrict__ qb, __hip_bfloat16* __restrict__ kb,
    __hip_bfloat16* __restrict__ vt) {
  __shared__ __align__(16) __hip_bfloat16 As[32][72];  // 32 rows x 64 k (+8 pad)
  const int tid = threadIdx.x;
  const int wave = tid >> 6;
  const int lane = tid & 63;
  const int g = lane >> 4;
  const int lr = lane & 15;
  const int m0 = blockIdx.x * 32;
  const int wr = (wave & 1) * 16;       // row offset within tile
  const int ntb = (wave >> 1) * 6;      // col-tile base

  f32x4 acc[6];
#pragma unroll
  for (int i = 0; i < 6; ++i) acc[i] = f32x4{0.f, 0.f, 0.f, 0.f};

  const int srow = tid >> 4;        // 0..31
  const int scol = (tid & 15) * 4;  // 0..60

  for (int k0 = 0; k0 < D_EMB; k0 += 64) {
    __syncthreads();
    {
      const float4 f =
          *reinterpret_cast<const float4*>(x + (size_t)(m0 + srow) * D_EMB + k0 + scol);
      __hip_bfloat16* dst = &As[srow][scol];
      dst[0] = __float2bfloat16(f.x);
      dst[1] = __float2bfloat16(f.y);
      dst[2] = __float2bfloat16(f.z);
      dst[3] = __float2bfloat16(f.w);
    }
    __syncthreads();
    bf16x8 a0 = *reinterpret_cast<const bf16x8*>(&As[wr + lr][g * 8]);
    bf16x8 a1 = *reinterpret_cast<const bf16x8*>(&As[wr + lr][32 + g * 8]);
#pragma unroll
    for (int nt = 0; nt < 6; ++nt) {
      const __hip_bfloat16* bp =
          Wt + (size_t)((ntb + nt) * 16 + lr) * D_EMB + k0 + g * 8;
      bf16x8 b0 = *reinterpret_cast<const bf16x8*>(bp);
      bf16x8 b1 = *reinterpret_cast<const bf16x8*>(bp + 32);
      acc[nt] = __builtin_amdgcn_mfma_f32_16x16x32_bf16(a0, b0, acc[nt], 0, 0, 0);
      acc[nt] = __builtin_amdgcn_mfma_f32_16x16x32_bf16(a1, b1, acc[nt], 0, 0, 0);
    }
  }

  const int rowbase = m0 + wr + g * 4;
#pragma unroll
  for (int nt = 0; nt < 6; ++nt) {
    const int n = (ntb + nt) * 16 + lr;  // 0..383
    const int head = n >> 7;             // 0:q 1:k 2:v
    const int h = n & 127;
#pragma unroll
    for (int r = 0; r < 4; ++r) {
      const int row = rowbase + r;  // global token index
      const __hip_bfloat16 val = __float2bfloat16(acc[nt][r]);
      if (head == 0) {
        qb[(size_t)row * H_DIM + h] = val;
      } else if (head == 1) {
        kb[(size_t)row * H_DIM + h] = val;
      } else {
        const int bi = row >> 11;  // /T_SEQ
        const int t = row & (T_SEQ - 1);
        vt[((size_t)bi * H_DIM + h) * T_SEQ + t] = val;
      }
    }
  }
}

// Flash attention, key-parallel within block:
// grid = B * T/16 blocks; block = 8 waves, all owning the same 16 q rows.
// Wave w processes key-blocks kb ≡ w (mod 8) with private (m,l,O), then a
// 3-round LDS tree merge combines the 8 partials.
__global__ __launch_bounds__(512) void attn_kernel(
    const __hip_bfloat16* __restrict__ qb, const __hip_bfloat16* __restrict__ kb,
    const __hip_bfloat16* __restrict__ vt, float* __restrict__ out) {
  __shared__ __align__(16) float Obuf[4][16][132];       // 33 KB merge buffer
  __shared__ float mbuf[8][16];
  __shared__ float lbuf[8][16];
  __shared__ __align__(16) __hip_bfloat16 Pl[8][16][40];  // per-wave P tile
  const int tid = threadIdx.x;
  const int wave = tid >> 6;
  const int lane = tid & 63;
  const int g = lane >> 4;
  const int lr = lane & 15;
  const int idx = blockIdx.x;
  const int b = idx & 7;                // batch fast -> spreads K/V reuse
  const int rg = 127 - (idx >> 3);      // heavy row-groups dispatched first
  const int qr0 = rg * 16;

  const __hip_bfloat16* qB = qb + (size_t)b * T_SEQ * H_DIM;
  const __hip_bfloat16* kB = kb + (size_t)b * T_SEQ * H_DIM;
  const __hip_bfloat16* vB = vt + (size_t)b * H_DIM * T_SEQ;

  // Q A-fragments (same 16 rows for all waves), hoisted
  bf16x8 qf[4];
#pragma unroll
  for (int kt = 0; kt < 4; ++kt)
    qf[kt] = *reinterpret_cast<const bf16x8*>(
        qB + (size_t)(qr0 + lr) * H_DIM + kt * 32 + g * 8);

  f32x4 oacc[8];
#pragma unroll
  for (int i = 0; i < 8; ++i) oacc[i] = f32x4{0.f, 0.f, 0.f, 0.f};
  float mrow[4] = {-1e30f, -1e30f, -1e30f, -1e30f};
  float lrow[4] = {0.f, 0.f, 0.f, 0.f};

  const float scale = 0.08838834764831845f;  // 1/sqrt(128)
  const int nkb = (qr0 + 16 + 31) >> 5;      // key-blocks needed (32 keys each)

  for (int kbi = wave; kbi < nkb; kbi += 8) {
    const int s0 = kbi * 32;
    // ---- S = Q K^T for 16 rows x 32 keys ----
    f32x4 sacc[2];
    sacc[0] = f32x4{0.f, 0.f, 0.f, 0.f};
    sacc[1] = f32x4{0.f, 0.f, 0.f, 0.f};
#pragma unroll
    for (int nt = 0; nt < 2; ++nt) {
#pragma unroll
      for (int kt = 0; kt < 4; ++kt) {
        bf16x8 kf = *reinterpret_cast<const bf16x8*>(
            kB + (size_t)(s0 + nt * 16 + lr) * H_DIM + kt * 32 + g * 8);
        sacc[nt] =
            __builtin_amdgcn_mfma_f32_16x16x32_bf16(qf[kt], kf, sacc[nt], 0, 0, 0);
      }
    }
    // ---- scale + causal mask ----
    float sv[2][4];
#pragma unroll
    for (int nt = 0; nt < 2; ++nt)
#pragma unroll
      for (int r = 0; r < 4; ++r) {
        const int key = s0 + nt * 16 + lr;
        const int qr = qr0 + g * 4 + r;
        const float s = sacc[nt][r] * scale;
        sv[nt][r] = (key > qr) ? -1e30f : s;
      }
    // ---- row max over 32 keys ----
    float pm[4];
#pragma unroll
    for (int r = 0; r < 4; ++r) pm[r] = fmaxf(sv[0][r], sv[1][r]);
#pragma unroll
    for (int m = 1; m < 16; m <<= 1)
#pragma unroll
      for (int r = 0; r < 4; ++r) pm[r] = fmaxf(pm[r], __shfl_xor(pm[r], m, 64));
    // ---- online softmax update ----
    float corr[4];
#pragma unroll
    for (int r = 0; r < 4; ++r) {
      const float mnew = fmaxf(mrow[r], pm[r]);
      corr[r] = __expf(mrow[r] - mnew);
      mrow[r] = mnew;
    }
    float rs[4];
#pragma unroll
    for (int r = 0; r < 4; ++r) {
      const float p0 = __expf(sv[0][r] - mrow[r]);
      const float p1 = __expf(sv[1][r] - mrow[r]);
      Pl[wave][g * 4 + r][lr] = __float2bfloat16(p0);
      Pl[wave][g * 4 + r][16 + lr] = __float2bfloat16(p1);
      rs[r] = p0 + p1;
    }
#pragma unroll
    for (int m = 1; m < 16; m <<= 1)
#pragma unroll
      for (int r = 0; r < 4; ++r) rs[r] += __shfl_xor(rs[r], m, 64);
#pragma unroll
    for (int r = 0; r < 4; ++r) lrow[r] = lrow[r] * corr[r] + rs[r];
#pragma unroll
    for (int ht = 0; ht < 8; ++ht)
#pragma unroll
      for (int r = 0; r < 4; ++r) oacc[ht][r] *= corr[r];

    // ---- PV: A = P[16x32] (LDS re-layout, wave-private), B = V^T rows ----
    asm volatile("" ::: "memory");
    bf16x8 pf = *reinterpret_cast<const bf16x8*>(&Pl[wave][lr][g * 8]);
#pragma unroll
    for (int ht = 0; ht < 8; ++ht) {
      bf16x8 vf = *reinterpret_cast<const bf16x8*>(
          vB + (size_t)(ht * 16 + lr) * T_SEQ + s0 + g * 8);
      oacc[ht] = __builtin_amdgcn_mfma_f32_16x16x32_bf16(pf, vf, oacc[ht], 0, 0, 0);
    }
  }

  // ---- cross-wave merge (3-round tree through LDS) ----
  if (lr == 0) {
#pragma unroll
    for (int r = 0; r < 4; ++r) {
      mbuf[wave][g * 4 + r] = mrow[r];
      lbuf[wave][g * 4 + r] = lrow[r];
    }
  }
  __syncthreads();
#pragma unroll
  for (int half = 4; half >= 1; half >>= 1) {
    if (wave >= half && wave < 2 * half) {
#pragma unroll
      for (int ht = 0; ht < 8; ++ht)
#pragma unroll
        for (int r = 0; r < 4; ++r)
          Obuf[wave - half][g * 4 + r][ht * 16 + lr] = oacc[ht][r];
    }
    __syncthreads();
    if (wave < half) {
      float a[4], bt[4];
#pragma unroll
      for (int r = 0; r < 4; ++r) {
        const float mB = mbuf[wave + half][g * 4 + r];
        const float lB = lbuf[wave + half][g * 4 + r];
        const float M = fmaxf(mrow[r], mB);
        a[r] = __expf(mrow[r] - M);
        bt[r] = __expf(mB - M);
        lrow[r] = a[r] * lrow[r] + bt[r] * lB;
        mrow[r] = M;
      }
#pragma unroll
      for (int ht = 0; ht < 8; ++ht)
#pragma unroll
        for (int r = 0; r < 4; ++r)
          oacc[ht][r] =
              a[r] * oacc[ht][r] + bt[r] * Obuf[wave][g * 4 + r][ht * 16 + lr];
      if (lr == 0) {
#pragma unroll
        for (int r = 0; r < 4; ++r) {
          mbuf[wave][g * 4 + r] = mrow[r];
          lbuf[wave][g * 4 + r] = lrow[r];
        }
      }
    }
    __syncthreads();
  }

  // ---- epilogue: wave 0 normalizes and stores fp32 ----
  if (wave == 0) {
#pragma unroll
    for (int ht = 0; ht < 8; ++ht)
#pragma unroll
      for (int r = 0; r < 4; ++r) {
        const int qr = qr0 + g * 4 + r;
        out[((size_t)b * T_SEQ + qr) * H_DIM + ht * 16 + lr] =
            oacc[ht][r] / lrow[r];
      }
  }
}

extern "C" void kernel_launch(void* const* d_in, const int* in_sizes, int n_in,
                              void* d_out, int out_size, void* d_ws, size_t ws_size,
                              hipStream_t stream) {
  const float* x = (const float*)d_in[0];
  const float* Wq = (const float*)d_in[1];
  const float* Wk = (const float*)d_in[2];
  const float* Wv = (const float*)d_in[3];
  float* out = (float*)d_out;

  __hip_bfloat16* Wt = (__hip_bfloat16*)d_ws;
  __hip_bfloat16* qbuf = Wt + (size_t)3 * 128 * 1024;
  __hip_bfloat16* kbuf = qbuf + (size_t)NTOK * H_DIM;
  __hip_bfloat16* vbuf = kbuf + (size_t)NTOK * H_DIM;

  hipLaunchKernelGGL(prep_w_kernel, dim3(384), dim3(256), 0, stream, Wq, Wk, Wv, Wt);
  hipLaunchKernelGGL(proj_kernel, dim3(512), dim3(512), 0, stream, x, Wt, qbuf,
                     kbuf, vbuf);
  hipLaunchKernelGGL(attn_kernel, dim3(1024), dim3(512), 0, stream, qbuf, kbuf,
                     vbuf, out);
}

// Round 3
// 117.254 us; speedup vs baseline: 2.6875x; 1.5459x over previous
//
#include <hip/hip_runtime.h>
#include <hip/hip_bf16.h>
#include <stdint.h>

typedef float f32x4 __attribute__((ext_vector_type(4)));
typedef __bf16 bf16x8 __attribute__((ext_vector_type(8)));

#define T_SEQ 2048
#define D_EMB 1024
#define H_DIM 128
#define NBATCH 8
#define NTOK 16384  // NBATCH * T_SEQ

typedef __attribute__((address_space(3))) uint32_t lds_u32;
typedef const __attribute__((address_space(1))) uint32_t glb_u32;

// ---------------------------------------------------------------------------
// ws layout (bf16 elements):
//   Wt : [3][128][1024]   transposed weights (W^T), q|k|v
//   qb : [16384][128]     Q bf16
//   kb : [16384][128]     K bf16
//   vt : [8][128][2048]   V transposed per batch (PV B-frags contiguous)
// ---------------------------------------------------------------------------

__global__ __launch_bounds__(256) void prep_w_kernel(
    const float* __restrict__ Wq, const float* __restrict__ Wk,
    const float* __restrict__ Wv, __hip_bfloat16* __restrict__ Wt) {
  const int mat = blockIdx.x >> 7;   // 0..2
  const int h = blockIdx.x & 127;
  const float* W = (mat == 0) ? Wq : ((mat == 1) ? Wk : Wv);
  __hip_bfloat16* dst = Wt + (size_t)(mat * 128 + h) * D_EMB;
  for (int k = threadIdx.x; k < D_EMB; k += 256)
    dst[k] = __float2bfloat16(W[(size_t)k * H_DIM + h]);
}

// Projection GEMM, m97-style: C[16384,384] = xb * Wt^T.
// BM=64 x BN=384 (full N -> x read exactly once) x BK=64.
// 8 waves; wave w owns cols w*48..w*48+47 (3 n-frags x 4 m-frags).
// B staged via global_load_lds (linear LDS); A staged fp32->bf16 reg-side
// with XOR swizzle (write & read both XOR col by (row&7)*8 elems).
__global__ __launch_bounds__(512) void proj_kernel(
    const float* __restrict__ x, const __hip_bfloat16* __restrict__ Wt,
    __hip_bfloat16* __restrict__ qb, __hip_bfloat16* __restrict__ kb,
    __hip_bfloat16* __restrict__ vt) {
  __shared__ __align__(16) __hip_bfloat16 As[64 * 64];    // 8 KB
  __shared__ __align__(16) __hip_bfloat16 Bs[384 * 64];   // 48 KB
  const int tid = threadIdx.x;
  const int wave = tid >> 6;
  const int lane = tid & 63;
  const int g = lane >> 4;
  const int lr = lane & 15;
  const int m0 = blockIdx.x * 64;
  const int wc = wave * 48;

  f32x4 acc[4][3];
#pragma unroll
  for (int m = 0; m < 4; ++m)
#pragma unroll
    for (int n = 0; n < 3; ++n) acc[m][n] = f32x4{0.f, 0.f, 0.f, 0.f};

  const int arow = tid >> 3;        // 0..63
  const int acol = (tid & 7) * 8;   // 0..56
  const float* asrc = x + (size_t)(m0 + arow) * D_EMB + acol;
  __hip_bfloat16* adst = &As[arow * 64 + (acol ^ ((arow & 7) * 8))];

  for (int k0 = 0; k0 < D_EMB; k0 += 64) {
    __syncthreads();
    // ---- B stage: Wt rows 0..383, k-slice k0..k0+63, linear LDS ----
#pragma unroll
    for (int i = 0; i < 6; ++i) {
      const int e = (i * 512 + tid) * 8;   // bf16 element index
      const int br = e >> 6;
      const int bc = e & 63;
      __builtin_amdgcn_global_load_lds(
          (glb_u32*)(uintptr_t)(Wt + (size_t)br * D_EMB + k0 + bc),
          (lds_u32*)(uintptr_t)(&Bs[e]), 16, 0, 0);
    }
    // ---- A stage: fp32 -> bf16, swizzled ds_write_b128 ----
    {
      const float4 f0 = *reinterpret_cast<const float4*>(asrc + k0);
      const float4 f1 = *reinterpret_cast<const float4*>(asrc + k0 + 4);
      union { bf16x8 v; __hip_bfloat16 h[8]; } u;
      u.h[0] = __float2bfloat16(f0.x);
      u.h[1] = __float2bfloat16(f0.y);
      u.h[2] = __float2bfloat16(f0.z);
      u.h[3] = __float2bfloat16(f0.w);
      u.h[4] = __float2bfloat16(f1.x);
      u.h[5] = __float2bfloat16(f1.y);
      u.h[6] = __float2bfloat16(f1.z);
      u.h[7] = __float2bfloat16(f1.w);
      *reinterpret_cast<bf16x8*>(adst) = u.v;
    }
    __syncthreads();
    // ---- compute: 2 kk-slices x (4 m x 3 n) MFMA ----
#pragma unroll
    for (int kk = 0; kk < 2; ++kk) {
      bf16x8 a[4];
#pragma unroll
      for (int m = 0; m < 4; ++m) {
        const int row = m * 16 + lr;
        a[m] = *reinterpret_cast<const bf16x8*>(
            &As[row * 64 + ((kk * 32 + g * 8) ^ ((row & 7) * 8))]);
      }
#pragma unroll
      for (int n = 0; n < 3; ++n) {
        bf16x8 b = *reinterpret_cast<const bf16x8*>(
            &Bs[(size_t)(wc + n * 16 + lr) * 64 + kk * 32 + g * 8]);
#pragma unroll
        for (int m = 0; m < 4; ++m)
          acc[m][n] =
              __builtin_amdgcn_mfma_f32_16x16x32_bf16(a[m], b, acc[m][n], 0, 0, 0);
      }
    }
  }

  // ---- store: C layout col=lane&15, row=(lane>>4)*4+reg ----
#pragma unroll
  for (int n = 0; n < 3; ++n) {
    const int ng = wc + n * 16 + lr;  // 0..383
    const int head = ng >> 7;         // 0:q 1:k 2:v
    const int h = ng & 127;
#pragma unroll
    for (int m = 0; m < 4; ++m) {
#pragma unroll
      for (int r = 0; r < 4; ++r) {
        const int row = m0 + m * 16 + g * 4 + r;  // global token
        const __hip_bfloat16 val = __float2bfloat16(acc[m][n][r]);
        if (head == 0) {
          qb[(size_t)row * H_DIM + h] = val;
        } else if (head == 1) {
          kb[(size_t)row * H_DIM + h] = val;
        } else {
          const int bi = row >> 11;
          const int t = row & (T_SEQ - 1);
          vt[((size_t)bi * H_DIM + h) * T_SEQ + t] = val;
        }
      }
    }
  }
}

// Flash attention, key-parallel within block:
// grid = B * T/16 blocks; block = 8 waves, all owning the same 16 q rows.
// Wave w processes key-blocks kb ≡ w (mod 8) with private (m,l,O), then a
// 3-round LDS tree merge combines the 8 partials.
__global__ __launch_bounds__(512) void attn_kernel(
    const __hip_bfloat16* __restrict__ qb, const __hip_bfloat16* __restrict__ kb,
    const __hip_bfloat16* __restrict__ vt, float* __restrict__ out) {
  __shared__ __align__(16) float Obuf[4][16][132];       // 33 KB merge buffer
  __shared__ float mbuf[8][16];
  __shared__ float lbuf[8][16];
  __shared__ __align__(16) __hip_bfloat16 Pl[8][16][40];  // per-wave P tile
  const int tid = threadIdx.x;
  const int wave = tid >> 6;
  const int lane = tid & 63;
  const int g = lane >> 4;
  const int lr = lane & 15;
  const int idx = blockIdx.x;
  const int b = idx & 7;                // batch fast -> spreads K/V reuse
  const int rg = 127 - (idx >> 3);      // heavy row-groups dispatched first
  const int qr0 = rg * 16;

  const __hip_bfloat16* qB = qb + (size_t)b * T_SEQ * H_DIM;
  const __hip_bfloat16* kB = kb + (size_t)b * T_SEQ * H_DIM;
  const __hip_bfloat16* vB = vt + (size_t)b * H_DIM * T_SEQ;

  // Q A-fragments (same 16 rows for all waves), hoisted
  bf16x8 qf[4];
#pragma unroll
  for (int kt = 0; kt < 4; ++kt)
    qf[kt] = *reinterpret_cast<const bf16x8*>(
        qB + (size_t)(qr0 + lr) * H_DIM + kt * 32 + g * 8);

  f32x4 oacc[8];
#pragma unroll
  for (int i = 0; i < 8; ++i) oacc[i] = f32x4{0.f, 0.f, 0.f, 0.f};
  float mrow[4] = {-1e30f, -1e30f, -1e30f, -1e30f};
  float lrow[4] = {0.f, 0.f, 0.f, 0.f};

  const float scale = 0.08838834764831845f;  // 1/sqrt(128)
  const int nkb = (qr0 + 16 + 31) >> 5;      // key-blocks needed (32 keys each)

  for (int kbi = wave; kbi < nkb; kbi += 8) {
    const int s0 = kbi * 32;
    // ---- S = Q K^T for 16 rows x 32 keys ----
    f32x4 sacc[2];
    sacc[0] = f32x4{0.f, 0.f, 0.f, 0.f};
    sacc[1] = f32x4{0.f, 0.f, 0.f, 0.f};
#pragma unroll
    for (int nt = 0; nt < 2; ++nt) {
#pragma unroll
      for (int kt = 0; kt < 4; ++kt) {
        bf16x8 kf = *reinterpret_cast<const bf16x8*>(
            kB + (size_t)(s0 + nt * 16 + lr) * H_DIM + kt * 32 + g * 8);
        sacc[nt] =
            __builtin_amdgcn_mfma_f32_16x16x32_bf16(qf[kt], kf, sacc[nt], 0, 0, 0);
      }
    }
    // ---- scale + causal mask ----
    float sv[2][4];
#pragma unroll
    for (int nt = 0; nt < 2; ++nt)
#pragma unroll
      for (int r = 0; r < 4; ++r) {
        const int key = s0 + nt * 16 + lr;
        const int qr = qr0 + g * 4 + r;
        const float s = sacc[nt][r] * scale;
        sv[nt][r] = (key > qr) ? -1e30f : s;
      }
    // ---- row max over 32 keys ----
    float pm[4];
#pragma unroll
    for (int r = 0; r < 4; ++r) pm[r] = fmaxf(sv[0][r], sv[1][r]);
#pragma unroll
    for (int m = 1; m < 16; m <<= 1)
#pragma unroll
      for (int r = 0; r < 4; ++r) pm[r] = fmaxf(pm[r], __shfl_xor(pm[r], m, 64));
    // ---- online softmax update ----
    float corr[4];
#pragma unroll
    for (int r = 0; r < 4; ++r) {
      const float mnew = fmaxf(mrow[r], pm[r]);
      corr[r] = __expf(mrow[r] - mnew);
      mrow[r] = mnew;
    }
    float rs[4];
#pragma unroll
    for (int r = 0; r < 4; ++r) {
      const float p0 = __expf(sv[0][r] - mrow[r]);
      const float p1 = __expf(sv[1][r] - mrow[r]);
      Pl[wave][g * 4 + r][lr] = __float2bfloat16(p0);
      Pl[wave][g * 4 + r][16 + lr] = __float2bfloat16(p1);
      rs[r] = p0 + p1;
    }
#pragma unroll
    for (int m = 1; m < 16; m <<= 1)
#pragma unroll
      for (int r = 0; r < 4; ++r) rs[r] += __shfl_xor(rs[r], m, 64);
#pragma unroll
    for (int r = 0; r < 4; ++r) lrow[r] = lrow[r] * corr[r] + rs[r];
#pragma unroll
    for (int ht = 0; ht < 8; ++ht)
#pragma unroll
      for (int r = 0; r < 4; ++r) oacc[ht][r] *= corr[r];

    // ---- PV: A = P[16x32] (LDS re-layout, wave-private), B = V^T rows ----
    asm volatile("" ::: "memory");
    bf16x8 pf = *reinterpret_cast<const bf16x8*>(&Pl[wave][lr][g * 8]);
#pragma unroll
    for (int ht = 0; ht < 8; ++ht) {
      bf16x8 vf = *reinterpret_cast<const bf16x8*>(
          vB + (size_t)(ht * 16 + lr) * T_SEQ + s0 + g * 8);
      oacc[ht] = __builtin_amdgcn_mfma_f32_16x16x32_bf16(pf, vf, oacc[ht], 0, 0, 0);
    }
  }

  // ---- cross-wave merge (3-round tree through LDS) ----
  if (lr == 0) {
#pragma unroll
    for (int r = 0; r < 4; ++r) {
      mbuf[wave][g * 4 + r] = mrow[r];
      lbuf[wave][g * 4 + r] = lrow[r];
    }
  }
  __syncthreads();
#pragma unroll
  for (int half = 4; half >= 1; half >>= 1) {
    if (wave >= half && wave < 2 * half) {
#pragma unroll
      for (int ht = 0; ht < 8; ++ht)
#pragma unroll
        for (int r = 0; r < 4; ++r)
          Obuf[wave - half][g * 4 + r][ht * 16 + lr] = oacc[ht][r];
    }
    __syncthreads();
    if (wave < half) {
      float a[4], bt[4];
#pragma unroll
      for (int r = 0; r < 4; ++r) {
        const float mB = mbuf[wave + half][g * 4 + r];
        const float lB = lbuf[wave + half][g * 4 + r];
        const float M = fmaxf(mrow[r], mB);
        a[r] = __expf(mrow[r] - M);
        bt[r] = __expf(mB - M);
        lrow[r] = a[r] * lrow[r] + bt[r] * lB;
        mrow[r] = M;
      }
#pragma unroll
      for (int ht = 0; ht < 8; ++ht)
#pragma unroll
        for (int r = 0; r < 4; ++r)
          oacc[ht][r] =
              a[r] * oacc[ht][r] + bt[r] * Obuf[wave][g * 4 + r][ht * 16 + lr];
      if (lr == 0) {
#pragma unroll
        for (int r = 0; r < 4; ++r) {
          mbuf[wave][g * 4 + r] = mrow[r];
          lbuf[wave][g * 4 + r] = lrow[r];
        }
      }
    }
    __syncthreads();
  }

  // ---- epilogue: wave 0 normalizes and stores fp32 ----
  if (wave == 0) {
#pragma unroll
    for (int ht = 0; ht < 8; ++ht)
#pragma unroll
      for (int r = 0; r < 4; ++r) {
        const int qr = qr0 + g * 4 + r;
        out[((size_t)b * T_SEQ + qr) * H_DIM + ht * 16 + lr] =
            oacc[ht][r] / lrow[r];
      }
  }
}

extern "C" void kernel_launch(void* const* d_in, const int* in_sizes, int n_in,
                              void* d_out, int out_size, void* d_ws, size_t ws_size,
                              hipStream_t stream) {
  const float* x = (const float*)d_in[0];
  const float* Wq = (const float*)d_in[1];
  const float* Wk = (const float*)d_in[2];
  const float* Wv = (const float*)d_in[3];
  float* out = (float*)d_out;

  __hip_bfloat16* Wt = (__hip_bfloat16*)d_ws;
  __hip_bfloat16* qbuf = Wt + (size_t)3 * 128 * 1024;
  __hip_bfloat16* kbuf = qbuf + (size_t)NTOK * H_DIM;
  __hip_bfloat16* vbuf = kbuf + (size_t)NTOK * H_DIM;

  hipLaunchKernelGGL(prep_w_kernel, dim3(384), dim3(256), 0, stream, Wq, Wk, Wv, Wt);
  hipLaunchKernelGGL(proj_kernel, dim3(256), dim3(512), 0, stream, x, Wt, qbuf,
                     kbuf, vbuf);
  hipLaunchKernelGGL(attn_kernel, dim3(1024), dim3(512), 0, stream, qbuf, kbuf,
                     vbuf, out);
}